// Round 2
// baseline (194.527 us; speedup 1.0000x reference)
//
#include <hip/hip_runtime.h>
#include <hip/hip_bf16.h>

namespace {

constexpr int IMG_H = 512;
constexpr int IMG_W = 512;
constexpr int BATCH = 64;
constexpr int RT = 8;                          // output rows per wave
constexpr int WAVES = 4;                       // waves per block
constexpr int ROWS_PER_BLOCK = RT * WAVES;     // 32
constexpr int BLOCKS_PER_IMG = IMG_H / ROWS_PER_BLOCK;  // 16
constexpr int GRID = BATCH * BLOCKS_PER_IMG;   // 1024
constexpr int NPART = GRID * WAVES;            // 4096 partial sums
constexpr float C1 = 1.6384f;                  // (0.01*128)^2
constexpr float C2 = 14.7456f;                 // (0.03*128)^2
constexpr float INV121 = 1.0f / 121.0f;

__device__ __forceinline__ float shup1(float v) { return __shfl_up(v, 1, 64); }
__device__ __forceinline__ float shdn1(float v) { return __shfl_down(v, 1, 64); }

// Vertical-window update: add (ADD) or subtract (!ADD) row r's raw quantities
// {x, y, x*x, y*y, x*y} into V[5][8] for this lane's 8 columns.
// Out-of-range rows (zero padding) are a wave-uniform no-op.
template <bool ADD>
__device__ __forceinline__ void vrow_acc(const float* __restrict__ p1,
                                         const float* __restrict__ p2,
                                         int r, int c0, float V[5][8])
{
  if ((unsigned)r >= (unsigned)IMG_H) return;  // wave-uniform branch
  const float4* a1 = reinterpret_cast<const float4*>(p1 + (size_t)r * IMG_W + c0);
  const float4* a2 = reinterpret_cast<const float4*>(p2 + (size_t)r * IMG_W + c0);
  float4 xa = a1[0], xb = a1[1];
  float4 ya = a2[0], yb = a2[1];
  float ox[8] = {xa.x, xa.y, xa.z, xa.w, xb.x, xb.y, xb.z, xb.w};
  float oy[8] = {ya.x, ya.y, ya.z, ya.w, yb.x, yb.y, yb.z, yb.w};
#pragma unroll
  for (int k = 0; k < 8; ++k) {
    float x = ox[k], y = oy[k];
    if (ADD) {
      V[0][k] += x;       V[1][k] += y;
      V[2][k] += x * x;   V[3][k] += y * y;   V[4][k] += x * y;
    } else {
      V[0][k] -= x;       V[1][k] -= y;
      V[2][k] -= x * x;   V[3][k] -= y * y;   V[4][k] -= x * y;
    }
  }
}

// Horizontal 11-box sliding sum over V (once per output row), then the SSIM
// map for this lane's 8 pixels; returns their sum.
__device__ __forceinline__ float ssim_from_V(const float V[5][8], int lane)
{
  float H[5][8];
  const bool l0 = (lane == 0), l63 = (lane == 63);
#pragma unroll
  for (int q = 0; q < 5; ++q) {
    float w[18];  // cols [c0-5, c0+12]; wave edges = image zero padding
#pragma unroll
    for (int i = 0; i < 8; ++i) w[5 + i] = V[q][i];
#pragma unroll
    for (int i = 0; i < 5; ++i) {
      float t = shup1(V[q][3 + i]);
      w[i] = l0 ? 0.f : t;
      float b = shdn1(V[q][i]);
      w[13 + i] = l63 ? 0.f : b;
    }
    float h = w[0];
#pragma unroll
    for (int j = 1; j < 11; ++j) h += w[j];
    H[q][0] = h;
#pragma unroll
    for (int k = 1; k < 8; ++k) {
      h += w[k + 10] - w[k - 1];
      H[q][k] = h;
    }
  }

  float rs = 0.f;
#pragma unroll
  for (int k = 0; k < 8; ++k) {
    float mu1 = H[0][k] * INV121;
    float mu2 = H[1][k] * INV121;
    float m11 = mu1 * mu1, m22 = mu2 * mu2, m12 = mu1 * mu2;
    float s1  = H[2][k] * INV121 - m11;
    float s2  = H[3][k] * INV121 - m22;
    float s12 = H[4][k] * INV121 - m12;
    float n1 = 2.f * m12 + C1;
    float n2 = 2.f * s12 + C2;
    float d1 = m11 + m22 + C1;
    float d2 = s1 + s2 + C2;
    float den = d1 * d2;                 // >= C1*C2 > 0
    float rc = __builtin_amdgcn_rcpf(den);
    rc = rc * (2.f - den * rc);          // one Newton step
    rs += (n1 * n2) * rc;
  }
  return rs;
}

} // namespace

__global__ __launch_bounds__(256, 4) void ssim_main(
    const float* __restrict__ img1, const float* __restrict__ img2,
    float* __restrict__ partials)
{
  const int tid = threadIdx.x;
  const int wave = tid >> 6;
  const int lane = tid & 63;
  const int gb = blockIdx.x;
  const int b  = gb >> 4;                 // batch (16 row-blocks per image)
  const int rb = gb & 15;
  const int y0 = rb * ROWS_PER_BLOCK + wave * RT;
  const int c0 = lane * 8;
  const float* p1 = img1 + (size_t)b * IMG_H * IMG_W;
  const float* p2 = img2 + (size_t)b * IMG_H * IMG_W;

  float V[5][8];
#pragma unroll
  for (int q = 0; q < 5; ++q)
#pragma unroll
    for (int k = 0; k < 8; ++k) V[q][k] = 0.f;

  // warm-up: V = sum of raw-quantity rows [y0-5, y0+5]
#pragma unroll 1
  for (int d = -5; d <= 5; ++d) vrow_acc<true>(p1, p2, y0 + d, c0, V);

  float acc = ssim_from_V(V, lane);

  // slide the 11-row vertical window down the strip
#pragma unroll 1
  for (int y = y0 + 1; y < y0 + RT; ++y) {
    vrow_acc<true >(p1, p2, y + 5, c0, V);
    vrow_acc<false>(p1, p2, y - 6, c0, V);
    acc += ssim_from_V(V, lane);
  }

  // wave reduction -> one float partial per wave
#pragma unroll
  for (int off = 32; off > 0; off >>= 1) acc += __shfl_down(acc, off, 64);
  if (lane == 0) partials[gb * WAVES + wave] = acc;
}

__global__ void ssim_reduce(const float* __restrict__ partials,
                            float* __restrict__ out)
{
  __shared__ double sd[256];
  const int tid = threadIdx.x;
  double s = 0.0;
  for (int i = tid; i < NPART; i += 256) s += (double)partials[i];
  sd[tid] = s;
  __syncthreads();
  for (int st = 128; st > 0; st >>= 1) {
    if (tid < st) sd[tid] += sd[tid + st];
    __syncthreads();
  }
  if (tid == 0) {
    double mean = sd[0] * (1.0 / 16777216.0);  // 64*512*512
    out[0] = (float)(1.0 - mean);
  }
}

extern "C" void kernel_launch(void* const* d_in, const int* in_sizes, int n_in,
                              void* d_out, int out_size, void* d_ws, size_t ws_size,
                              hipStream_t stream)
{
  const float* img1 = (const float*)d_in[0];
  const float* img2 = (const float*)d_in[1];
  // d_in[2] is the uniform 1/121 window; folded into INV121.
  float* out = (float*)d_out;
  float* partials = (float*)d_ws;  // NPART floats, fully overwritten each call

  ssim_main<<<dim3(GRID), dim3(256), 0, stream>>>(img1, img2, partials);
  ssim_reduce<<<dim3(1), dim3(256), 0, stream>>>(partials, out);
}

// Round 3
// 189.405 us; speedup vs baseline: 1.0270x; 1.0270x over previous
//
#include <hip/hip_runtime.h>
#include <hip/hip_bf16.h>

namespace {

constexpr int IMG_H = 512;
constexpr int IMG_W = 512;
constexpr int BATCH = 64;
constexpr int RT = 8;                          // output rows per wave
constexpr int WAVES = 4;                       // waves per block
constexpr int ROWS_PER_BLOCK = RT * WAVES;     // 32
constexpr int BLOCKS_PER_IMG = IMG_H / ROWS_PER_BLOCK;  // 16
constexpr int GRID = BATCH * BLOCKS_PER_IMG;   // 1024
constexpr int NPART = GRID * WAVES;            // 4096 partial sums
constexpr float C1 = 1.6384f;                  // (0.01*128)^2
constexpr float C2 = 14.7456f;                 // (0.03*128)^2
// normalization folded: scale numerator/denominator by 121^2
constexpr float C1S = C1 * 14641.0f;           // C1 * 121^2
constexpr float C2S = C2 * 14641.0f;           // C2 * 121^2

// DPP lane shifts on the VALU pipe (no LDS / lgkmcnt, unlike __shfl).
// wave_shr:1 = 0x138 (lane i <- lane i-1, lane0 <- 0 with bound_ctrl)
// wave_shl:1 = 0x130 (lane i <- lane i+1, lane63 <- 0 with bound_ctrl)
__device__ __forceinline__ float dpp_up1(float v) {
  int r = __builtin_amdgcn_mov_dpp(__builtin_bit_cast(int, v), 0x138, 0xF, 0xF, true);
  return __builtin_bit_cast(float, r);
}
__device__ __forceinline__ float dpp_dn1(float v) {
  int r = __builtin_amdgcn_mov_dpp(__builtin_bit_cast(int, v), 0x130, 0xF, 0xF, true);
  return __builtin_bit_cast(float, r);
}

// Vertical-window update: add (ADD) or subtract (!ADD) row r's raw quantities
// {x, y, x*x, y*y, x*y} into V[5][8] for this lane's 8 columns.
// Out-of-range rows (zero padding) are a wave-uniform no-op.
template <bool ADD>
__device__ __forceinline__ void vrow_acc(const float* __restrict__ p1,
                                         const float* __restrict__ p2,
                                         int r, int c0, float V[5][8])
{
  if ((unsigned)r >= (unsigned)IMG_H) return;  // wave-uniform branch
  const float4* a1 = reinterpret_cast<const float4*>(p1 + (size_t)r * IMG_W + c0);
  const float4* a2 = reinterpret_cast<const float4*>(p2 + (size_t)r * IMG_W + c0);
  float4 xa = a1[0], xb = a1[1];
  float4 ya = a2[0], yb = a2[1];
  float ox[8] = {xa.x, xa.y, xa.z, xa.w, xb.x, xb.y, xb.z, xb.w};
  float oy[8] = {ya.x, ya.y, ya.z, ya.w, yb.x, yb.y, yb.z, yb.w};
#pragma unroll
  for (int k = 0; k < 8; ++k) {
    float x = ox[k], y = oy[k];
    if (ADD) {
      V[0][k] += x;       V[1][k] += y;
      V[2][k] += x * x;   V[3][k] += y * y;   V[4][k] += x * y;
    } else {
      V[0][k] -= x;       V[1][k] -= y;
      V[2][k] -= x * x;   V[3][k] -= y * y;   V[4][k] -= x * y;
    }
  }
}

// Horizontal 11-box sliding sum over V (DPP halo), then the SSIM map for this
// lane's 8 pixels; returns their sum. Normalization folded into C1S/C2S.
__device__ __forceinline__ float ssim_from_V(const float V[5][8])
{
  float H[5][8];
#pragma unroll
  for (int q = 0; q < 5; ++q) {
    float w[18];  // cols [c0-5, c0+12]; DPP bound_ctrl zero-fills image edges
#pragma unroll
    for (int i = 0; i < 8; ++i) w[5 + i] = V[q][i];
#pragma unroll
    for (int i = 0; i < 5; ++i) {
      w[i]      = dpp_up1(V[q][3 + i]);   // lane-1's cols 3..7
      w[13 + i] = dpp_dn1(V[q][i]);       // lane+1's cols 0..4
    }
    float h = w[0];
#pragma unroll
    for (int j = 1; j < 11; ++j) h += w[j];
    H[q][0] = h;
#pragma unroll
    for (int k = 1; k < 8; ++k) {
      h += w[k + 10] - w[k - 1];
      H[q][k] = h;
    }
  }

  float rs = 0.f;
#pragma unroll
  for (int k = 0; k < 8; ++k) {
    float A = H[0][k], B = H[1][k];
    float AB   = A * B;
    float A2B2 = __builtin_fmaf(A, A, B * B);
    float t1 = __builtin_fmaf(2.0f, AB, C1S);            // 2AB + C1'
    float u1 = A2B2 + C1S;
    float t2 = __builtin_fmaf(242.0f, H[4][k], C2S);     // 2*121*H4 + C2'
    t2 = __builtin_fmaf(-2.0f, AB, t2);                  //  ... - 2AB
    float u2 = __builtin_fmaf(121.0f, H[2][k] + H[3][k], C2S) - A2B2;
    float num = t1 * t2;
    float den = u1 * u2;                                 // >= C1S*C2S > 0
    float rc = __builtin_amdgcn_rcpf(den);
    rc = rc * (2.f - den * rc);                          // one Newton step
    rs = __builtin_fmaf(num, rc, rs);
  }
  return rs;
}

} // namespace

__global__ __launch_bounds__(256, 4) void ssim_main(
    const float* __restrict__ img1, const float* __restrict__ img2,
    float* __restrict__ partials)
{
  const int tid = threadIdx.x;
  const int wave = tid >> 6;
  const int lane = tid & 63;
  const int gb = blockIdx.x;
  const int b  = gb >> 4;                 // batch (16 row-blocks per image)
  const int rb = gb & 15;
  const int y0 = rb * ROWS_PER_BLOCK + wave * RT;
  const int c0 = lane * 8;
  const float* p1 = img1 + (size_t)b * IMG_H * IMG_W;
  const float* p2 = img2 + (size_t)b * IMG_H * IMG_W;

  float V[5][8];
#pragma unroll
  for (int q = 0; q < 5; ++q)
#pragma unroll
    for (int k = 0; k < 8; ++k) V[q][k] = 0.f;

  // warm-up: V = sum of raw-quantity rows [y0-5, y0+5]
#pragma unroll 1
  for (int d = -5; d <= 5; ++d) vrow_acc<true>(p1, p2, y0 + d, c0, V);

  float acc = ssim_from_V(V);

  // slide the 11-row vertical window down the strip
#pragma unroll 1
  for (int y = y0 + 1; y < y0 + RT; ++y) {
    vrow_acc<true >(p1, p2, y + 5, c0, V);
    vrow_acc<false>(p1, p2, y - 6, c0, V);
    acc += ssim_from_V(V);
  }

  // wave reduction -> one float partial per wave
#pragma unroll
  for (int off = 32; off > 0; off >>= 1) acc += __shfl_down(acc, off, 64);
  if (lane == 0) partials[gb * WAVES + wave] = acc;
}

__global__ void ssim_reduce(const float* __restrict__ partials,
                            float* __restrict__ out)
{
  __shared__ double sd[256];
  const int tid = threadIdx.x;
  double s = 0.0;
  for (int i = tid; i < NPART; i += 256) s += (double)partials[i];
  sd[tid] = s;
  __syncthreads();
  for (int st = 128; st > 0; st >>= 1) {
    if (tid < st) sd[tid] += sd[tid + st];
    __syncthreads();
  }
  if (tid == 0) {
    double mean = sd[0] * (1.0 / 16777216.0);  // 64*512*512
    out[0] = (float)(1.0 - mean);
  }
}

extern "C" void kernel_launch(void* const* d_in, const int* in_sizes, int n_in,
                              void* d_out, int out_size, void* d_ws, size_t ws_size,
                              hipStream_t stream)
{
  const float* img1 = (const float*)d_in[0];
  const float* img2 = (const float*)d_in[1];
  // d_in[2] is the uniform 1/121 window; folded into the scaled constants.
  float* out = (float*)d_out;
  float* partials = (float*)d_ws;  // NPART floats, fully overwritten each call

  ssim_main<<<dim3(GRID), dim3(256), 0, stream>>>(img1, img2, partials);
  ssim_reduce<<<dim3(1), dim3(256), 0, stream>>>(partials, out);
}